// Round 1
// baseline (5081.837 us; speedup 1.0000x reference)
//
#include <hip/hip_runtime.h>

#define BB 8
#define NN 8192
#define MM 2048
#define KK 32
#define NTOT (BB*MM*KK)   // 524288

// ws layout (float offsets)
#define WS_PTS_T  0          // 4,194,304 f  (B,N,64)
#define WS_XYZN   4194304    // 1,048,576 f  (B,N) float4
#define WS_IDX    5242880    //   524,288 i  (B,M,32)
#define WS_GPART  5767168    //   524,288 f  [s*128+o][2048]
#define WS_PARAMS 6291456    //     1,024 f  layer*256 + {A[0..127], C[128..255]}
#define WS_ZMAX   6292480    // 2,097,152 f
#define WS_ZMIN   8389632    // 2,097,152 f
#define WS_TOTAL  10486784

// ---------------- transpose points (B,64,N) -> (B,N,64) ----------------
__global__ __launch_bounds__(256) void k_transpose(const float* __restrict__ pts,
                                                   float* __restrict__ pts_t){
  __shared__ float tile[64][65];
  int bid = blockIdx.x;
  int b = bid >> 7;                 // 128 tiles per batch
  int n0 = (bid & 127) << 6;
  int tx = threadIdx.x & 63, ty = threadIdx.x >> 6;
  const float* src = pts + (size_t)b*64*NN;
  #pragma unroll
  for (int c = ty; c < 64; c += 4)
    tile[c][tx] = src[(size_t)c*NN + n0 + tx];
  __syncthreads();
  float* dst = pts_t + ((size_t)b*NN + n0)*64;
  #pragma unroll
  for (int r = ty; r < 64; r += 4)
    dst[(size_t)r*64 + tx] = tile[tx][r];
}

// ---------------- xyz + norm staging (B,N) float4 ----------------
__global__ __launch_bounds__(256) void k_xyzn(const float* __restrict__ xyz,
                                              float4* __restrict__ xyzn){
  #pragma clang fp contract(off)
  int i = blockIdx.x*256 + threadIdx.x;   // 65536
  int b = i >> 13, n = i & 8191;
  const float* p = xyz + (size_t)b*3*NN;
  float x = p[n], y = p[NN+n], z = p[2*NN+n];
  float nrm = (x*x + y*y) + z*z;
  xyzn[i] = make_float4(x, y, z, nrm);
}

// ---------------- farthest point sampling ----------------
__global__ __launch_bounds__(1024) void k_fps(const float* __restrict__ xyz,
                                              float* __restrict__ out_newxyz){
  #pragma clang fp contract(off)
  __shared__ float sx[NN], sy[NN], sz[NN];
  __shared__ float swv[16];
  __shared__ int   swi[16];
  int b = blockIdx.x, tid = threadIdx.x;
  const float* xb = xyz + (size_t)b*3*NN;
  float px[8], py[8], pz[8], dd[8];
  #pragma unroll
  for (int i = 0; i < 8; ++i){
    int n = tid + i*1024;
    px[i] = xb[n]; py[i] = xb[NN+n]; pz[i] = xb[2*NN+n];
    sx[n] = px[i]; sy[n] = py[i]; sz[n] = pz[i];
    dd[i] = 1e10f;
  }
  __syncthreads();
  float cx = sx[0], cy = sy[0], cz = sz[0];  // far = 0 initially
  float* ob = out_newxyz + (size_t)b*3*MM;
  int lane = tid & 63, wid = tid >> 6;
  for (int t = 0; t < MM; ++t){
    if (tid == 0){ ob[t] = cx; ob[MM+t] = cy; ob[2*MM+t] = cz; }
    float bv = -1.0f; int bi = 0;
    #pragma unroll
    for (int i = 0; i < 8; ++i){
      float dx = px[i]-cx, dy = py[i]-cy, dz = pz[i]-cz;
      float d = (dx*dx + dy*dy) + dz*dz;       // linear sum, no fma (matches np)
      float nd = fminf(dd[i], d);
      dd[i] = nd;
      if (nd > bv){ bv = nd; bi = tid + i*1024; }  // ascending n -> first-max kept
    }
    #pragma unroll
    for (int off = 1; off < 64; off <<= 1){
      float ov = __shfl_xor(bv, off);
      int   oi = __shfl_xor(bi, off);
      if (ov > bv || (ov == bv && oi < bi)){ bv = ov; bi = oi; }
    }
    if (lane == 0){ swv[wid] = bv; swi[wid] = bi; }
    __syncthreads();
    float rv = (lane < 16) ? swv[lane] : -1.0f;
    int   ri = (lane < 16) ? swi[lane] : 0x7fffffff;
    #pragma unroll
    for (int off = 1; off < 16; off <<= 1){
      float ov = __shfl_xor(rv, off);
      int   oi = __shfl_xor(ri, off);
      if (ov > rv || (ov == rv && oi < ri)){ rv = ov; ri = oi; }
    }
    int far = __shfl(ri, 0);
    cx = sx[far]; cy = sy[far]; cz = sz[far];
    __syncthreads();   // protect swv/swi for next iteration
  }
}

// ---------------- ball query ----------------
__global__ __launch_bounds__(256) void k_ballq(const float4* __restrict__ xyzn,
                                               const float* __restrict__ newxyz,
                                               int* __restrict__ idx){
  #pragma clang fp contract(off)
  __shared__ float4 sp[NN];
  const float R2 = (float)(0.2*0.2);
  int b = blockIdx.x >> 6;                 // 64 blocks per batch
  int m0 = (blockIdx.x & 63) << 5;         // 32 centroids per block
  const float4* src = xyzn + (size_t)b*NN;
  for (int i = threadIdx.x; i < NN; i += 256) sp[i] = src[i];
  __syncthreads();
  int wv = threadIdx.x >> 6, lane = threadIdx.x & 63;
  const float* nb = newxyz + (size_t)b*3*MM;
  for (int mi = wv; mi < 32; mi += 4){
    int m = m0 + mi;
    float cx = nb[m], cy = nb[MM+m], cz = nb[2*MM+m];
    float cn = (cx*cx + cy*cy) + cz*cz;
    int* om = idx + ((size_t)(b*MM + m))*KK;
    int filled = 0, first = 0; bool hasFirst = false;
    for (int ch = 0; ch < NN/64; ++ch){
      int j = ch*64 + lane;
      float4 p = sp[j];
      float dot = (cx*p.x + cy*p.y) + cz*p.z;   // linear, no fma (matches np einsum)
      float sq = (cn + p.w) - 2.0f*dot;
      bool pred = sq < R2;
      unsigned long long mask = __ballot(pred);
      if (mask){
        if (!hasFirst){ first = ch*64 + __builtin_ctzll(mask); hasFirst = true; }
        int cnt = __popcll(mask);
        if (pred){
          int rank = __popcll(mask & ((1ull << lane) - 1ull));
          int slot = filled + rank;
          if (slot < KK) om[slot] = j;
        }
        filled += cnt;
        if (filled >= KK) break;
      }
    }
    if (filled < KK){
      int pad = hasFirst ? first : 0;
      for (int s = filled + lane; s < KK; s += 64) om[s] = pad;
    }
  }
}

// ---------------- conv helpers ----------------
__device__ __forceinline__ void accum_ch(float4* acc, const float4* w4, int c, float v){
  #pragma unroll
  for (int o4 = 0; o4 < 16; ++o4){
    float4 w = w4[c*16 + o4];
    acc[o4].x = fmaf(w.x, v, acc[o4].x);
    acc[o4].y = fmaf(w.y, v, acc[o4].y);
    acc[o4].z = fmaf(w.z, v, acc[o4].z);
    acc[o4].w = fmaf(w.w, v, acc[o4].w);
  }
}

// conv1 for one position (m,k): z1[64] from gathered 67-channel input
__device__ __forceinline__ void conv1_pos(float4* acc, const float* s_w1,
    const float* pts_t, const float4* xyzn, const float* nb, int b, int m, int j){
  #pragma unroll
  for (int o4 = 0; o4 < 16; ++o4) acc[o4] = make_float4(0.f,0.f,0.f,0.f);
  float4 P = xyzn[(size_t)b*NN + j];
  float x0 = P.x - nb[m], x1 = P.y - nb[MM+m], x2 = P.z - nb[2*MM+m];
  const float4* w4 = (const float4*)s_w1;
  accum_ch(acc, w4, 0, x0);
  accum_ch(acc, w4, 1, x1);
  accum_ch(acc, w4, 2, x2);
  const float4* pf = (const float4*)(pts_t + ((size_t)b*NN + j)*64);
  #pragma unroll
  for (int c4 = 0; c4 < 16; ++c4){
    float4 v = pf[c4];
    accum_ch(acc, w4, 3+4*c4+0, v.x);
    accum_ch(acc, w4, 3+4*c4+1, v.y);
    accum_ch(acc, w4, 3+4*c4+2, v.z);
    accum_ch(acc, w4, 3+4*c4+3, v.w);
  }
}

// ---------------- K4: conv1 -> stats1 ----------------
__global__ __launch_bounds__(256,1) void k_conv1_stats(const float* __restrict__ pts_t,
    const float4* __restrict__ xyzn, const float* __restrict__ newxyz,
    const int* __restrict__ idx, const float* __restrict__ W1, float* __restrict__ gpart){
  __shared__ float s_w1[67*64];
  __shared__ float s_z[256*68];
  __shared__ float s_part[4*64*2];
  int tid = threadIdx.x;
  for (int i = tid; i < 67*64; i += 256){ int c = i>>6, o = i&63; s_w1[i] = W1[o*67 + c]; }
  __syncthreads();
  int bid = blockIdx.x, b = bid >> 8, m0 = (bid & 255) << 3;
  int m = m0 + (tid >> 5), k = tid & 31;
  int j = idx[((size_t)(b*MM + m))*KK + k];
  const float* nb = newxyz + (size_t)b*3*MM;
  float4 acc[16];
  conv1_pos(acc, s_w1, pts_t, xyzn, nb, b, m, j);
  #pragma unroll
  for (int o4 = 0; o4 < 16; ++o4) *(float4*)&s_z[tid*68 + o4*4] = acc[o4];
  __syncthreads();
  int o = tid & 63, q = tid >> 6;
  float s = 0.f, sq = 0.f;
  for (int p = q*64; p < q*64 + 64; ++p){ float v = s_z[p*68 + o]; s += v; sq = fmaf(v, v, sq); }
  s_part[(q*64+o)*2] = s; s_part[(q*64+o)*2+1] = sq;
  __syncthreads();
  if (tid < 64){
    float S = 0.f, SQ = 0.f;
    #pragma unroll
    for (int qq = 0; qq < 4; ++qq){ S += s_part[(qq*64+tid)*2]; SQ += s_part[(qq*64+tid)*2+1]; }
    gpart[(size_t)tid*2048 + bid] = S;
    gpart[(size_t)(128+tid)*2048 + bid] = SQ;
  }
}

// ---------------- BN finalize: deterministic f64 reduce ----------------
__global__ __launch_bounds__(256) void k_bnfin(const float* __restrict__ gpart,
    const float* __restrict__ g, const float* __restrict__ be, float* __restrict__ params){
  int o = blockIdx.x, t = threadIdx.x;
  double s = 0.0, sq = 0.0;
  for (int i = t; i < 2048; i += 256){
    s  += (double)gpart[(size_t)o*2048 + i];
    sq += (double)gpart[(size_t)(128+o)*2048 + i];
  }
  __shared__ double ds[256], dq[256];
  ds[t] = s; dq[t] = sq; __syncthreads();
  for (int off = 128; off > 0; off >>= 1){
    if (t < off){ ds[t] += ds[t+off]; dq[t] += dq[t+off]; }
    __syncthreads();
  }
  if (t == 0){
    double mu = ds[0] / (double)NTOT;
    double var = dq[0] / (double)NTOT - mu*mu;
    float A = g[o] / sqrtf((float)var + 1e-5f);
    float Cc = be[o] - (float)mu * A;
    params[o] = A; params[128+o] = Cc;
  }
}

// ---------------- K5: conv1 -> bn1/relu -> conv2 -> stats2 ----------------
__global__ __launch_bounds__(256,1) void k_conv2_stats(const float* __restrict__ pts_t,
    const float4* __restrict__ xyzn, const float* __restrict__ newxyz,
    const int* __restrict__ idx, const float* __restrict__ W1, const float* __restrict__ W2,
    const float* __restrict__ params1, float* __restrict__ gpart){
  __shared__ float s_w1[67*64];
  __shared__ float s_w2[64*64];
  __shared__ float s_p[128];
  __shared__ float s_z[256*68];
  __shared__ float s_part[4*64*2];
  int tid = threadIdx.x;
  for (int i = tid; i < 67*64; i += 256){ int c = i>>6, o = i&63; s_w1[i] = W1[o*67 + c]; }
  for (int i = tid; i < 64*64; i += 256){ int c = i>>6, o = i&63; s_w2[i] = W2[o*64 + c]; }
  if (tid < 64){ s_p[tid] = params1[tid]; s_p[64+tid] = params1[128+tid]; }
  __syncthreads();
  int bid = blockIdx.x, b = bid >> 8, m0 = (bid & 255) << 3;
  int m = m0 + (tid >> 5), k = tid & 31;
  int j = idx[((size_t)(b*MM + m))*KK + k];
  const float* nb = newxyz + (size_t)b*3*MM;
  float4 acc[16];
  conv1_pos(acc, s_w1, pts_t, xyzn, nb, b, m, j);
  float4 h[16];
  #pragma unroll
  for (int o4 = 0; o4 < 16; ++o4){
    float4 z = acc[o4], hh;
    hh.x = fmaxf(fmaf(s_p[4*o4+0], z.x, s_p[64+4*o4+0]), 0.f);
    hh.y = fmaxf(fmaf(s_p[4*o4+1], z.y, s_p[64+4*o4+1]), 0.f);
    hh.z = fmaxf(fmaf(s_p[4*o4+2], z.z, s_p[64+4*o4+2]), 0.f);
    hh.w = fmaxf(fmaf(s_p[4*o4+3], z.w, s_p[64+4*o4+3]), 0.f);
    h[o4] = hh;
  }
  float4 a2[16];
  #pragma unroll
  for (int o4 = 0; o4 < 16; ++o4) a2[o4] = make_float4(0.f,0.f,0.f,0.f);
  const float4* w24 = (const float4*)s_w2;
  #pragma unroll
  for (int c4 = 0; c4 < 16; ++c4){
    accum_ch(a2, w24, 4*c4+0, h[c4].x);
    accum_ch(a2, w24, 4*c4+1, h[c4].y);
    accum_ch(a2, w24, 4*c4+2, h[c4].z);
    accum_ch(a2, w24, 4*c4+3, h[c4].w);
  }
  #pragma unroll
  for (int o4 = 0; o4 < 16; ++o4) *(float4*)&s_z[tid*68 + o4*4] = a2[o4];
  __syncthreads();
  int o = tid & 63, q = tid >> 6;
  float s = 0.f, sq = 0.f;
  for (int p = q*64; p < q*64 + 64; ++p){ float v = s_z[p*68 + o]; s += v; sq = fmaf(v, v, sq); }
  s_part[(q*64+o)*2] = s; s_part[(q*64+o)*2+1] = sq;
  __syncthreads();
  if (tid < 64){
    float S = 0.f, SQ = 0.f;
    #pragma unroll
    for (int qq = 0; qq < 4; ++qq){ S += s_part[(qq*64+tid)*2]; SQ += s_part[(qq*64+tid)*2+1]; }
    gpart[(size_t)tid*2048 + bid] = S;
    gpart[(size_t)(128+tid)*2048 + bid] = SQ;
  }
}

// ---------------- K6: chain -> conv3 -> stats3 + per-m max/min over k ----------------
__global__ __launch_bounds__(256,1) void k_conv3(const float* __restrict__ pts_t,
    const float4* __restrict__ xyzn, const float* __restrict__ newxyz,
    const int* __restrict__ idx, const float* __restrict__ W1, const float* __restrict__ W2,
    const float* __restrict__ W3, const float* __restrict__ params1,
    const float* __restrict__ params2, float* __restrict__ gpart,
    float* __restrict__ zmax, float* __restrict__ zmin){
  __shared__ float s_w1[67*64];
  __shared__ float s_w2[64*64];
  __shared__ float s_p[256];
  __shared__ float s_z[256*68];
  __shared__ float s_sm[8*128*2];
  int tid = threadIdx.x;
  for (int i = tid; i < 67*64; i += 256){ int c = i>>6, o = i&63; s_w1[i] = W1[o*67 + c]; }
  for (int i = tid; i < 64*64; i += 256){ int c = i>>6, o = i&63; s_w2[i] = W2[o*64 + c]; }
  if (tid < 64){
    s_p[tid]      = params1[tid];     s_p[64+tid]  = params1[128+tid];
    s_p[128+tid]  = params2[tid];     s_p[192+tid] = params2[128+tid];
  }
  __syncthreads();
  int bid = blockIdx.x, b = bid >> 8, m0 = (bid & 255) << 3;
  {
    int m = m0 + (tid >> 5), k = tid & 31;
    int j = idx[((size_t)(b*MM + m))*KK + k];
    const float* nb = newxyz + (size_t)b*3*MM;
    float4 acc[16];
    conv1_pos(acc, s_w1, pts_t, xyzn, nb, b, m, j);
    float4 h[16];
    #pragma unroll
    for (int o4 = 0; o4 < 16; ++o4){
      float4 z = acc[o4], hh;
      hh.x = fmaxf(fmaf(s_p[4*o4+0], z.x, s_p[64+4*o4+0]), 0.f);
      hh.y = fmaxf(fmaf(s_p[4*o4+1], z.y, s_p[64+4*o4+1]), 0.f);
      hh.z = fmaxf(fmaf(s_p[4*o4+2], z.z, s_p[64+4*o4+2]), 0.f);
      hh.w = fmaxf(fmaf(s_p[4*o4+3], z.w, s_p[64+4*o4+3]), 0.f);
      h[o4] = hh;
    }
    float4 a2[16];
    #pragma unroll
    for (int o4 = 0; o4 < 16; ++o4) a2[o4] = make_float4(0.f,0.f,0.f,0.f);
    const float4* w24 = (const float4*)s_w2;
    #pragma unroll
    for (int c4 = 0; c4 < 16; ++c4){
      accum_ch(a2, w24, 4*c4+0, h[c4].x);
      accum_ch(a2, w24, 4*c4+1, h[c4].y);
      accum_ch(a2, w24, 4*c4+2, h[c4].z);
      accum_ch(a2, w24, 4*c4+3, h[c4].w);
    }
    // h2 = relu(A2*z2+C2) -> stash
    #pragma unroll
    for (int o4 = 0; o4 < 16; ++o4){
      float4 z = a2[o4], hh;
      hh.x = fmaxf(fmaf(s_p[128+4*o4+0], z.x, s_p[192+4*o4+0]), 0.f);
      hh.y = fmaxf(fmaf(s_p[128+4*o4+1], z.y, s_p[192+4*o4+1]), 0.f);
      hh.z = fmaxf(fmaf(s_p[128+4*o4+2], z.z, s_p[192+4*o4+2]), 0.f);
      hh.w = fmaxf(fmaf(s_p[128+4*o4+3], z.w, s_p[192+4*o4+3]), 0.f);
      *(float4*)&s_z[tid*68 + o4*4] = hh;
    }
  }
  __syncthreads();
  // phase2: conv3 from stash; thread = (ml in 8, og in 32), o = og*4..+3, all 32 k
  int ml = tid >> 5, og = tid & 31;
  float accK[4][32];
  #pragma unroll
  for (int oo = 0; oo < 4; ++oo)
    #pragma unroll
    for (int k2 = 0; k2 < 32; ++k2) accK[oo][k2] = 0.f;
  const float4* w3g = (const float4*)W3;   // row o = 16 float4 (from global; per-lane rows)
  #pragma unroll
  for (int c4 = 0; c4 < 16; ++c4){
    float4 w[4];
    #pragma unroll
    for (int oo = 0; oo < 4; ++oo) w[oo] = w3g[(og*4+oo)*16 + c4];
    #pragma unroll
    for (int k2 = 0; k2 < 32; ++k2){
      float4 hv = *(const float4*)&s_z[(ml*32+k2)*68 + c4*4];
      #pragma unroll
      for (int oo = 0; oo < 4; ++oo){
        accK[oo][k2] = fmaf(w[oo].x, hv.x, accK[oo][k2]);
        accK[oo][k2] = fmaf(w[oo].y, hv.y, accK[oo][k2]);
        accK[oo][k2] = fmaf(w[oo].z, hv.z, accK[oo][k2]);
        accK[oo][k2] = fmaf(w[oo].w, hv.w, accK[oo][k2]);
      }
    }
  }
  int m = m0 + ml;
  #pragma unroll
  for (int oo = 0; oo < 4; ++oo){
    float mx = -3.4e38f, mn = 3.4e38f, s = 0.f, sq = 0.f;
    #pragma unroll
    for (int k2 = 0; k2 < 32; ++k2){
      float v = accK[oo][k2];
      mx = fmaxf(mx, v); mn = fminf(mn, v);
      s += v; sq = fmaf(v, v, sq);
    }
    int o = og*4 + oo;
    zmax[((size_t)(b*128 + o))*MM + m] = mx;
    zmin[((size_t)(b*128 + o))*MM + m] = mn;
    s_sm[(ml*128+o)*2] = s; s_sm[(ml*128+o)*2+1] = sq;
  }
  __syncthreads();
  {
    int o = tid >> 1, st = tid & 1;
    float S = 0.f;
    #pragma unroll
    for (int mm = 0; mm < 8; ++mm) S += s_sm[(mm*128+o)*2 + st];
    gpart[(size_t)(st*128+o)*2048 + bid] = S;
  }
}

// ---------------- final output: bn3 affine on max/min, relu ----------------
__global__ __launch_bounds__(256) void k_out(const float* __restrict__ zmax,
    const float* __restrict__ zmin, const float* __restrict__ params3,
    float* __restrict__ out){
  int i = blockIdx.x*256 + threadIdx.x;   // 2,097,152
  int o = (i >> 11) & 127;
  float A = params3[o], Cc = params3[128+o];
  float v = (A >= 0.f) ? fmaf(A, zmax[i], Cc) : fmaf(A, zmin[i], Cc);
  out[49152 + i] = fmaxf(v, 0.f);
}

extern "C" void kernel_launch(void* const* d_in, const int* in_sizes, int n_in,
                              void* d_out, int out_size, void* d_ws, size_t ws_size,
                              hipStream_t stream){
  const float* xyz    = (const float*)d_in[0];
  const float* points = (const float*)d_in[1];
  const float* W1  = (const float*)d_in[2];
  const float* g1  = (const float*)d_in[4];
  const float* be1 = (const float*)d_in[5];
  const float* W2  = (const float*)d_in[6];
  const float* g2  = (const float*)d_in[8];
  const float* be2 = (const float*)d_in[9];
  const float* W3  = (const float*)d_in[10];
  const float* g3  = (const float*)d_in[12];
  const float* be3 = (const float*)d_in[13];

  if (ws_size < (size_t)WS_TOTAL * sizeof(float)) return;  // need ~42 MB scratch

  float*  ws     = (float*)d_ws;
  float*  pts_t  = ws + WS_PTS_T;
  float4* xyzn   = (float4*)(ws + WS_XYZN);
  int*    idx    = (int*)(ws + WS_IDX);
  float*  gpart  = ws + WS_GPART;
  float*  params = ws + WS_PARAMS;
  float*  zmax   = ws + WS_ZMAX;
  float*  zmin   = ws + WS_ZMIN;
  float*  out    = (float*)d_out;
  float*  newxyz = out;   // (B,3,M) at offset 0

  hipLaunchKernelGGL(k_transpose, dim3(1024), dim3(256), 0, stream, points, pts_t);
  hipLaunchKernelGGL(k_xyzn,      dim3(256),  dim3(256), 0, stream, xyz, xyzn);
  hipLaunchKernelGGL(k_fps,       dim3(8),    dim3(1024),0, stream, xyz, newxyz);
  hipLaunchKernelGGL(k_ballq,     dim3(512),  dim3(256), 0, stream, xyzn, newxyz, idx);
  hipLaunchKernelGGL(k_conv1_stats, dim3(2048), dim3(256), 0, stream,
                     pts_t, xyzn, newxyz, idx, W1, gpart);
  hipLaunchKernelGGL(k_bnfin, dim3(64), dim3(256), 0, stream, gpart, g1, be1, params+0);
  hipLaunchKernelGGL(k_conv2_stats, dim3(2048), dim3(256), 0, stream,
                     pts_t, xyzn, newxyz, idx, W1, W2, params+0, gpart);
  hipLaunchKernelGGL(k_bnfin, dim3(64), dim3(256), 0, stream, gpart, g2, be2, params+256);
  hipLaunchKernelGGL(k_conv3, dim3(2048), dim3(256), 0, stream,
                     pts_t, xyzn, newxyz, idx, W1, W2, W3, params+0, params+256,
                     gpart, zmax, zmin);
  hipLaunchKernelGGL(k_bnfin, dim3(128), dim3(256), 0, stream, gpart, g3, be3, params+512);
  hipLaunchKernelGGL(k_out, dim3(8192), dim3(256), 0, stream, zmax, zmin, params+512, out);
}

// Round 2
// 3320.662 us; speedup vs baseline: 1.5304x; 1.5304x over previous
//
#include <hip/hip_runtime.h>

#define BB 8
#define NN 8192
#define MM 2048
#define KK 32
#define NTOT (BB*MM*KK)   // 524288

// ws layout (float offsets)
#define WS_PTS_T  0          // 4,194,304 f  (B,N,64)
#define WS_XYZN   4194304    // 1,048,576 f  (B,N) float4
#define WS_IDX    5242880    //   524,288 i  (B,M,32)
#define WS_GPART  5767168    //   524,288 f  [s*128+o][2048]
#define WS_PARAMS 6291456    //     1,024 f  layer*256 + {A[0..127], C[128..255]}
#define WS_ZMAX   6292480    // 2,097,152 f
#define WS_ZMIN   8389632    // 2,097,152 f
#define WS_TOTAL  10486784

// ---------------- transpose points (B,64,N) -> (B,N,64) ----------------
__global__ __launch_bounds__(256) void k_transpose(const float* __restrict__ pts,
                                                   float* __restrict__ pts_t){
  __shared__ float tile[64][65];
  int bid = blockIdx.x;
  int b = bid >> 7;                 // 128 tiles per batch
  int n0 = (bid & 127) << 6;
  int tx = threadIdx.x & 63, ty = threadIdx.x >> 6;
  const float* src = pts + (size_t)b*64*NN;
  #pragma unroll
  for (int c = ty; c < 64; c += 4)
    tile[c][tx] = src[(size_t)c*NN + n0 + tx];
  __syncthreads();
  float* dst = pts_t + ((size_t)b*NN + n0)*64;
  #pragma unroll
  for (int r = ty; r < 64; r += 4)
    dst[(size_t)r*64 + tx] = tile[tx][r];
}

// ---------------- xyz + norm staging (B,N) float4 ----------------
__global__ __launch_bounds__(256) void k_xyzn(const float* __restrict__ xyz,
                                              float4* __restrict__ xyzn){
  #pragma clang fp contract(off)
  int i = blockIdx.x*256 + threadIdx.x;   // 65536
  int b = i >> 13, n = i & 8191;
  const float* p = xyz + (size_t)b*3*NN;
  float x = p[n], y = p[NN+n], z = p[2*NN+n];
  float nrm = (x*x + y*y) + z*z;
  xyzn[i] = make_float4(x, y, z, nrm);
}

// ---------------- farthest point sampling ----------------
// 256 threads, 32 points/thread in registers. Packed u64 argmax key
// (fbits<<32 | ~idx): all dists >= 0 so float-bit order == value order;
// ties resolve to lowest global index (numpy argmax semantics).
// One barrier per iter via double-buffered cross-wave slots.
__global__ __launch_bounds__(256,1) void k_fps(const float* __restrict__ xyz,
                                               float* __restrict__ out_newxyz){
  #pragma clang fp contract(off)
  __shared__ float4 sp4[NN];                     // 128 KB
  __shared__ unsigned long long swk[2][4];
  int b = blockIdx.x, tid = threadIdx.x;
  const float* xb = xyz + (size_t)b*3*NN;
  float px[32], py[32], pz[32], dd[32];
  #pragma unroll
  for (int i = 0; i < 32; ++i){
    int n = tid + i*256;
    px[i] = xb[n]; py[i] = xb[NN+n]; pz[i] = xb[2*NN+n];
    sp4[n] = make_float4(px[i], py[i], pz[i], 0.f);
    dd[i] = 1e10f;
  }
  __syncthreads();
  float4 c0 = sp4[0];                            // far = 0 initially
  float cx = c0.x, cy = c0.y, cz = c0.z;
  float* ob = out_newxyz + (size_t)b*3*MM;
  int lane = tid & 63, wid = tid >> 6;
  for (int t = 0; t < MM; ++t){
    if (tid == 0){ ob[t] = cx; ob[MM+t] = cy; ob[2*MM+t] = cz; }
    float bv = -1.0f; int bi = 0;
    #pragma unroll
    for (int i = 0; i < 32; ++i){
      float dx = px[i]-cx, dy = py[i]-cy, dz = pz[i]-cz;
      float d = (dx*dx + dy*dy) + dz*dz;         // linear sum, no fma (matches np)
      float nd = fminf(dd[i], d);
      dd[i] = nd;
      bool gt = nd > bv;                          // strict > keeps first (lowest i)
      bv = gt ? nd : bv;
      bi = gt ? i : bi;
    }
    unsigned int gbi = (unsigned int)(tid + (bi << 8));   // global index
    unsigned long long key =
        ((unsigned long long)__float_as_uint(bv) << 32) | (unsigned int)(~gbi);
    #pragma unroll
    for (int off = 1; off < 64; off <<= 1){
      unsigned long long ok = __shfl_xor(key, off);
      key = (ok > key) ? ok : key;
    }
    int buf = t & 1;
    if (lane == 0) swk[buf][wid] = key;
    __syncthreads();
    unsigned long long k0 = swk[buf][0], k1 = swk[buf][1];
    unsigned long long k2 = swk[buf][2], k3 = swk[buf][3];
    unsigned long long ka = (k0 > k1) ? k0 : k1;
    unsigned long long kb = (k2 > k3) ? k2 : k3;
    unsigned long long km = (ka > kb) ? ka : kb;
    int far = (int)(~(unsigned int)km) & (NN-1);
    float4 c = sp4[far];
    cx = c.x; cy = c.y; cz = c.z;
  }
}

// ---------------- ball query: parallel mask build + serial emit ----------------
__global__ __launch_bounds__(256) void k_ballq(const float4* __restrict__ xyzn,
                                               const float* __restrict__ newxyz,
                                               int* __restrict__ idx){
  #pragma clang fp contract(off)
  __shared__ unsigned long long s_mask[32][129];   // padded: 2-way bank alias only
  __shared__ float4 s_c4[32];
  const float R2 = (float)(0.2*0.2);
  int b = blockIdx.x >> 6;                 // 64 blocks per batch
  int m0 = (blockIdx.x & 63) << 5;         // 32 centroids per block
  int tid = threadIdx.x, lane = tid & 63, wv = tid >> 6;
  const float* nb = newxyz + (size_t)b*3*MM;
  if (tid < 32){
    int m = m0 + tid;
    float cx = nb[m], cy = nb[MM+m], cz = nb[2*MM+m];
    float cn = (cx*cx + cy*cy) + cz*cz;
    s_c4[tid] = make_float4(cx, cy, cz, cn);
  }
  __syncthreads();
  const float4* src = xyzn + (size_t)b*NN;
  // phase A: break-free mask build; wave w owns chunks ch = 4k+w
  for (int ci = 0; ci < 32; ++ci){
    int ch = ci*4 + wv;
    float4 p = src[ch*64 + lane];
    #pragma unroll 8
    for (int mi = 0; mi < 32; ++mi){
      float4 c = s_c4[mi];
      float dot = (c.x*p.x + c.y*p.y) + c.z*p.z;   // linear, no fma (matches np)
      float sq = (c.w + p.w) - 2.0f*dot;
      unsigned long long mk = __ballot(sq < R2);
      if (lane == 0) s_mask[mi][ch] = mk;
    }
  }
  __syncthreads();
  // phase B: first 32 set bits in index order, pad with first hit (0 if none)
  if (tid < 32){
    int m = m0 + tid;
    int* om = idx + ((size_t)(b*MM + m))*KK;
    int filled = 0, first = -1;
    for (int ch = 0; ch < 128 && filled < KK; ++ch){
      unsigned long long mk = s_mask[tid][ch];
      while (mk){
        int bp = __builtin_ctzll(mk);
        mk &= mk - 1;
        int j = ch*64 + bp;
        if (first < 0) first = j;
        om[filled++] = j;
        if (filled == KK) break;
      }
    }
    int pad = (first < 0) ? 0 : first;
    for (int s = filled; s < KK; ++s) om[s] = pad;
  }
}

// ---------------- conv helpers ----------------
__device__ __forceinline__ void accum_ch(float4* acc, const float4* w4, int c, float v){
  #pragma unroll
  for (int o4 = 0; o4 < 16; ++o4){
    float4 w = w4[c*16 + o4];
    acc[o4].x = fmaf(w.x, v, acc[o4].x);
    acc[o4].y = fmaf(w.y, v, acc[o4].y);
    acc[o4].z = fmaf(w.z, v, acc[o4].z);
    acc[o4].w = fmaf(w.w, v, acc[o4].w);
  }
}

// conv1 for one position (m,k): z1[64] from gathered 67-channel input
__device__ __forceinline__ void conv1_pos(float4* acc, const float* s_w1,
    const float* pts_t, const float4* xyzn, const float* nb, int b, int m, int j){
  #pragma unroll
  for (int o4 = 0; o4 < 16; ++o4) acc[o4] = make_float4(0.f,0.f,0.f,0.f);
  float4 P = xyzn[(size_t)b*NN + j];
  float x0 = P.x - nb[m], x1 = P.y - nb[MM+m], x2 = P.z - nb[2*MM+m];
  const float4* w4 = (const float4*)s_w1;
  accum_ch(acc, w4, 0, x0);
  accum_ch(acc, w4, 1, x1);
  accum_ch(acc, w4, 2, x2);
  const float4* pf = (const float4*)(pts_t + ((size_t)b*NN + j)*64);
  #pragma unroll
  for (int c4 = 0; c4 < 16; ++c4){
    float4 v = pf[c4];
    accum_ch(acc, w4, 3+4*c4+0, v.x);
    accum_ch(acc, w4, 3+4*c4+1, v.y);
    accum_ch(acc, w4, 3+4*c4+2, v.z);
    accum_ch(acc, w4, 3+4*c4+3, v.w);
  }
}

// ---------------- K4: conv1 -> stats1 ----------------
__global__ __launch_bounds__(256,1) void k_conv1_stats(const float* __restrict__ pts_t,
    const float4* __restrict__ xyzn, const float* __restrict__ newxyz,
    const int* __restrict__ idx, const float* __restrict__ W1, float* __restrict__ gpart){
  __shared__ float s_w1[67*64];
  __shared__ float s_z[256*68];
  __shared__ float s_part[4*64*2];
  int tid = threadIdx.x;
  for (int i = tid; i < 67*64; i += 256){ int c = i>>6, o = i&63; s_w1[i] = W1[o*67 + c]; }
  __syncthreads();
  int bid = blockIdx.x, b = bid >> 8, m0 = (bid & 255) << 3;
  int m = m0 + (tid >> 5), k = tid & 31;
  int j = idx[((size_t)(b*MM + m))*KK + k];
  const float* nb = newxyz + (size_t)b*3*MM;
  float4 acc[16];
  conv1_pos(acc, s_w1, pts_t, xyzn, nb, b, m, j);
  #pragma unroll
  for (int o4 = 0; o4 < 16; ++o4) *(float4*)&s_z[tid*68 + o4*4] = acc[o4];
  __syncthreads();
  int o = tid & 63, q = tid >> 6;
  float s = 0.f, sq = 0.f;
  for (int p = q*64; p < q*64 + 64; ++p){ float v = s_z[p*68 + o]; s += v; sq = fmaf(v, v, sq); }
  s_part[(q*64+o)*2] = s; s_part[(q*64+o)*2+1] = sq;
  __syncthreads();
  if (tid < 64){
    float S = 0.f, SQ = 0.f;
    #pragma unroll
    for (int qq = 0; qq < 4; ++qq){ S += s_part[(qq*64+tid)*2]; SQ += s_part[(qq*64+tid)*2+1]; }
    gpart[(size_t)tid*2048 + bid] = S;
    gpart[(size_t)(128+tid)*2048 + bid] = SQ;
  }
}

// ---------------- BN finalize: deterministic f64 reduce ----------------
__global__ __launch_bounds__(256) void k_bnfin(const float* __restrict__ gpart,
    const float* __restrict__ g, const float* __restrict__ be, float* __restrict__ params){
  int o = blockIdx.x, t = threadIdx.x;
  double s = 0.0, sq = 0.0;
  for (int i = t; i < 2048; i += 256){
    s  += (double)gpart[(size_t)o*2048 + i];
    sq += (double)gpart[(size_t)(128+o)*2048 + i];
  }
  __shared__ double ds[256], dq[256];
  ds[t] = s; dq[t] = sq; __syncthreads();
  for (int off = 128; off > 0; off >>= 1){
    if (t < off){ ds[t] += ds[t+off]; dq[t] += dq[t+off]; }
    __syncthreads();
  }
  if (t == 0){
    double mu = ds[0] / (double)NTOT;
    double var = dq[0] / (double)NTOT - mu*mu;
    float A = g[o] / sqrtf((float)var + 1e-5f);
    float Cc = be[o] - (float)mu * A;
    params[o] = A; params[128+o] = Cc;
  }
}

// ---------------- K5: conv1 -> bn1/relu -> conv2 -> stats2 ----------------
__global__ __launch_bounds__(256,1) void k_conv2_stats(const float* __restrict__ pts_t,
    const float4* __restrict__ xyzn, const float* __restrict__ newxyz,
    const int* __restrict__ idx, const float* __restrict__ W1, const float* __restrict__ W2,
    const float* __restrict__ params1, float* __restrict__ gpart){
  __shared__ float s_w1[67*64];
  __shared__ float s_w2[64*64];
  __shared__ float s_p[128];
  __shared__ float s_z[256*68];
  __shared__ float s_part[4*64*2];
  int tid = threadIdx.x;
  for (int i = tid; i < 67*64; i += 256){ int c = i>>6, o = i&63; s_w1[i] = W1[o*67 + c]; }
  for (int i = tid; i < 64*64; i += 256){ int c = i>>6, o = i&63; s_w2[i] = W2[o*64 + c]; }
  if (tid < 64){ s_p[tid] = params1[tid]; s_p[64+tid] = params1[128+tid]; }
  __syncthreads();
  int bid = blockIdx.x, b = bid >> 8, m0 = (bid & 255) << 3;
  int m = m0 + (tid >> 5), k = tid & 31;
  int j = idx[((size_t)(b*MM + m))*KK + k];
  const float* nb = newxyz + (size_t)b*3*MM;
  float4 acc[16];
  conv1_pos(acc, s_w1, pts_t, xyzn, nb, b, m, j);
  float4 h[16];
  #pragma unroll
  for (int o4 = 0; o4 < 16; ++o4){
    float4 z = acc[o4], hh;
    hh.x = fmaxf(fmaf(s_p[4*o4+0], z.x, s_p[64+4*o4+0]), 0.f);
    hh.y = fmaxf(fmaf(s_p[4*o4+1], z.y, s_p[64+4*o4+1]), 0.f);
    hh.z = fmaxf(fmaf(s_p[4*o4+2], z.z, s_p[64+4*o4+2]), 0.f);
    hh.w = fmaxf(fmaf(s_p[4*o4+3], z.w, s_p[64+4*o4+3]), 0.f);
    h[o4] = hh;
  }
  float4 a2[16];
  #pragma unroll
  for (int o4 = 0; o4 < 16; ++o4) a2[o4] = make_float4(0.f,0.f,0.f,0.f);
  const float4* w24 = (const float4*)s_w2;
  #pragma unroll
  for (int c4 = 0; c4 < 16; ++c4){
    accum_ch(a2, w24, 4*c4+0, h[c4].x);
    accum_ch(a2, w24, 4*c4+1, h[c4].y);
    accum_ch(a2, w24, 4*c4+2, h[c4].z);
    accum_ch(a2, w24, 4*c4+3, h[c4].w);
  }
  #pragma unroll
  for (int o4 = 0; o4 < 16; ++o4) *(float4*)&s_z[tid*68 + o4*4] = a2[o4];
  __syncthreads();
  int o = tid & 63, q = tid >> 6;
  float s = 0.f, sq = 0.f;
  for (int p = q*64; p < q*64 + 64; ++p){ float v = s_z[p*68 + o]; s += v; sq = fmaf(v, v, sq); }
  s_part[(q*64+o)*2] = s; s_part[(q*64+o)*2+1] = sq;
  __syncthreads();
  if (tid < 64){
    float S = 0.f, SQ = 0.f;
    #pragma unroll
    for (int qq = 0; qq < 4; ++qq){ S += s_part[(qq*64+tid)*2]; SQ += s_part[(qq*64+tid)*2+1]; }
    gpart[(size_t)tid*2048 + bid] = S;
    gpart[(size_t)(128+tid)*2048 + bid] = SQ;
  }
}

// ---------------- K6: chain -> conv3 -> stats3 + per-m max/min over k ----------------
__global__ __launch_bounds__(256,1) void k_conv3(const float* __restrict__ pts_t,
    const float4* __restrict__ xyzn, const float* __restrict__ newxyz,
    const int* __restrict__ idx, const float* __restrict__ W1, const float* __restrict__ W2,
    const float* __restrict__ W3, const float* __restrict__ params1,
    const float* __restrict__ params2, float* __restrict__ gpart,
    float* __restrict__ zmax, float* __restrict__ zmin){
  __shared__ float s_w1[67*64];
  __shared__ float s_w2[64*64];
  __shared__ float s_p[256];
  __shared__ float s_z[256*68];
  __shared__ float s_sm[8*128*2];
  int tid = threadIdx.x;
  for (int i = tid; i < 67*64; i += 256){ int c = i>>6, o = i&63; s_w1[i] = W1[o*67 + c]; }
  for (int i = tid; i < 64*64; i += 256){ int c = i>>6, o = i&63; s_w2[i] = W2[o*64 + c]; }
  if (tid < 64){
    s_p[tid]      = params1[tid];     s_p[64+tid]  = params1[128+tid];
    s_p[128+tid]  = params2[tid];     s_p[192+tid] = params2[128+tid];
  }
  __syncthreads();
  int bid = blockIdx.x, b = bid >> 8, m0 = (bid & 255) << 3;
  {
    int m = m0 + (tid >> 5), k = tid & 31;
    int j = idx[((size_t)(b*MM + m))*KK + k];
    const float* nb = newxyz + (size_t)b*3*MM;
    float4 acc[16];
    conv1_pos(acc, s_w1, pts_t, xyzn, nb, b, m, j);
    float4 h[16];
    #pragma unroll
    for (int o4 = 0; o4 < 16; ++o4){
      float4 z = acc[o4], hh;
      hh.x = fmaxf(fmaf(s_p[4*o4+0], z.x, s_p[64+4*o4+0]), 0.f);
      hh.y = fmaxf(fmaf(s_p[4*o4+1], z.y, s_p[64+4*o4+1]), 0.f);
      hh.z = fmaxf(fmaf(s_p[4*o4+2], z.z, s_p[64+4*o4+2]), 0.f);
      hh.w = fmaxf(fmaf(s_p[4*o4+3], z.w, s_p[64+4*o4+3]), 0.f);
      h[o4] = hh;
    }
    float4 a2[16];
    #pragma unroll
    for (int o4 = 0; o4 < 16; ++o4) a2[o4] = make_float4(0.f,0.f,0.f,0.f);
    const float4* w24 = (const float4*)s_w2;
    #pragma unroll
    for (int c4 = 0; c4 < 16; ++c4){
      accum_ch(a2, w24, 4*c4+0, h[c4].x);
      accum_ch(a2, w24, 4*c4+1, h[c4].y);
      accum_ch(a2, w24, 4*c4+2, h[c4].z);
      accum_ch(a2, w24, 4*c4+3, h[c4].w);
    }
    // h2 = relu(A2*z2+C2) -> stash
    #pragma unroll
    for (int o4 = 0; o4 < 16; ++o4){
      float4 z = a2[o4], hh;
      hh.x = fmaxf(fmaf(s_p[128+4*o4+0], z.x, s_p[192+4*o4+0]), 0.f);
      hh.y = fmaxf(fmaf(s_p[128+4*o4+1], z.y, s_p[192+4*o4+1]), 0.f);
      hh.z = fmaxf(fmaf(s_p[128+4*o4+2], z.z, s_p[192+4*o4+2]), 0.f);
      hh.w = fmaxf(fmaf(s_p[128+4*o4+3], z.w, s_p[192+4*o4+3]), 0.f);
      *(float4*)&s_z[tid*68 + o4*4] = hh;
    }
  }
  __syncthreads();
  // phase2: conv3 from stash; thread = (ml in 8, og in 32), o = og*4..+3, all 32 k
  int ml = tid >> 5, og = tid & 31;
  float accK[4][32];
  #pragma unroll
  for (int oo = 0; oo < 4; ++oo)
    #pragma unroll
    for (int k2 = 0; k2 < 32; ++k2) accK[oo][k2] = 0.f;
  const float4* w3g = (const float4*)W3;   // row o = 16 float4 (from global; per-lane rows)
  #pragma unroll
  for (int c4 = 0; c4 < 16; ++c4){
    float4 w[4];
    #pragma unroll
    for (int oo = 0; oo < 4; ++oo) w[oo] = w3g[(og*4+oo)*16 + c4];
    #pragma unroll
    for (int k2 = 0; k2 < 32; ++k2){
      float4 hv = *(const float4*)&s_z[(ml*32+k2)*68 + c4*4];
      #pragma unroll
      for (int oo = 0; oo < 4; ++oo){
        accK[oo][k2] = fmaf(w[oo].x, hv.x, accK[oo][k2]);
        accK[oo][k2] = fmaf(w[oo].y, hv.y, accK[oo][k2]);
        accK[oo][k2] = fmaf(w[oo].z, hv.z, accK[oo][k2]);
        accK[oo][k2] = fmaf(w[oo].w, hv.w, accK[oo][k2]);
      }
    }
  }
  int m = m0 + ml;
  #pragma unroll
  for (int oo = 0; oo < 4; ++oo){
    float mx = -3.4e38f, mn = 3.4e38f, s = 0.f, sq = 0.f;
    #pragma unroll
    for (int k2 = 0; k2 < 32; ++k2){
      float v = accK[oo][k2];
      mx = fmaxf(mx, v); mn = fminf(mn, v);
      s += v; sq = fmaf(v, v, sq);
    }
    int o = og*4 + oo;
    zmax[((size_t)(b*128 + o))*MM + m] = mx;
    zmin[((size_t)(b*128 + o))*MM + m] = mn;
    s_sm[(ml*128+o)*2] = s; s_sm[(ml*128+o)*2+1] = sq;
  }
  __syncthreads();
  {
    int o = tid >> 1, st = tid & 1;
    float S = 0.f;
    #pragma unroll
    for (int mm = 0; mm < 8; ++mm) S += s_sm[(mm*128+o)*2 + st];
    gpart[(size_t)(st*128+o)*2048 + bid] = S;
  }
}

// ---------------- final output: bn3 affine on max/min, relu ----------------
__global__ __launch_bounds__(256) void k_out(const float* __restrict__ zmax,
    const float* __restrict__ zmin, const float* __restrict__ params3,
    float* __restrict__ out){
  int i = blockIdx.x*256 + threadIdx.x;   // 2,097,152
  int o = (i >> 11) & 127;
  float A = params3[o], Cc = params3[128+o];
  float v = (A >= 0.f) ? fmaf(A, zmax[i], Cc) : fmaf(A, zmin[i], Cc);
  out[49152 + i] = fmaxf(v, 0.f);
}

extern "C" void kernel_launch(void* const* d_in, const int* in_sizes, int n_in,
                              void* d_out, int out_size, void* d_ws, size_t ws_size,
                              hipStream_t stream){
  const float* xyz    = (const float*)d_in[0];
  const float* points = (const float*)d_in[1];
  const float* W1  = (const float*)d_in[2];
  const float* g1  = (const float*)d_in[4];
  const float* be1 = (const float*)d_in[5];
  const float* W2  = (const float*)d_in[6];
  const float* g2  = (const float*)d_in[8];
  const float* be2 = (const float*)d_in[9];
  const float* W3  = (const float*)d_in[10];
  const float* g3  = (const float*)d_in[12];
  const float* be3 = (const float*)d_in[13];

  if (ws_size < (size_t)WS_TOTAL * sizeof(float)) return;  // need ~42 MB scratch

  float*  ws     = (float*)d_ws;
  float*  pts_t  = ws + WS_PTS_T;
  float4* xyzn   = (float4*)(ws + WS_XYZN);
  int*    idx    = (int*)(ws + WS_IDX);
  float*  gpart  = ws + WS_GPART;
  float*  params = ws + WS_PARAMS;
  float*  zmax   = ws + WS_ZMAX;
  float*  zmin   = ws + WS_ZMIN;
  float*  out    = (float*)d_out;
  float*  newxyz = out;   // (B,3,M) at offset 0

  hipLaunchKernelGGL(k_fps,       dim3(8),    dim3(256), 0, stream, xyz, newxyz);
  hipLaunchKernelGGL(k_transpose, dim3(1024), dim3(256), 0, stream, points, pts_t);
  hipLaunchKernelGGL(k_xyzn,      dim3(256),  dim3(256), 0, stream, xyz, xyzn);
  hipLaunchKernelGGL(k_ballq,     dim3(512),  dim3(256), 0, stream, xyzn, newxyz, idx);
  hipLaunchKernelGGL(k_conv1_stats, dim3(2048), dim3(256), 0, stream,
                     pts_t, xyzn, newxyz, idx, W1, gpart);
  hipLaunchKernelGGL(k_bnfin, dim3(64), dim3(256), 0, stream, gpart, g1, be1, params+0);
  hipLaunchKernelGGL(k_conv2_stats, dim3(2048), dim3(256), 0, stream,
                     pts_t, xyzn, newxyz, idx, W1, W2, params+0, gpart);
  hipLaunchKernelGGL(k_bnfin, dim3(64), dim3(256), 0, stream, gpart, g2, be2, params+256);
  hipLaunchKernelGGL(k_conv3, dim3(2048), dim3(256), 0, stream,
                     pts_t, xyzn, newxyz, idx, W1, W2, W3, params+0, params+256,
                     gpart, zmax, zmin);
  hipLaunchKernelGGL(k_bnfin, dim3(128), dim3(256), 0, stream, gpart, g3, be3, params+512);
  hipLaunchKernelGGL(k_out, dim3(8192), dim3(256), 0, stream, zmax, zmin, params+512, out);
}